// Round 7
// baseline (258.986 us; speedup 1.0000x reference)
//
#include <hip/hip_runtime.h>
#include <math.h>

#define HID 64
#define HEADS 8
#define ALD 72

typedef __attribute__((ext_vector_type(8))) short bf16x8;
typedef __attribute__((ext_vector_type(4))) float f32x4;

// ---------------------------------------------------------------------------
// bf16 helpers (storage compression; accumulation stays f32)
// ---------------------------------------------------------------------------
__device__ __forceinline__ unsigned short f2bf(float f) {
    union { float f; unsigned int u; } cv; cv.f = f;
    unsigned int u = cv.u;
    unsigned int r = (u + 0x7FFFu + ((u >> 16) & 1u)) >> 16;  // RNE
    return (unsigned short)r;
}
__device__ __forceinline__ float bflo(unsigned int u) {
    union { unsigned int u; float f; } cv; cv.u = u << 16; return cv.f;
}
__device__ __forceinline__ float bfhi(unsigned int u) {
    union { unsigned int u; float f; } cv; cv.u = u & 0xFFFF0000u; return cv.f;
}
__device__ __forceinline__ unsigned relu_pk(unsigned u) {  // relu on 2 packed bf16
    unsigned m = ((u & 0x8000u) ? 0u : 0xFFFFu) |
                 ((u & 0x80000000u) ? 0u : 0xFFFF0000u);
    return u & m;
}

// packed bf16-pair dot with f32 accumulate: d = a.lo*b.lo + a.hi*b.hi + c
__device__ __forceinline__ float dot2bf(unsigned a, unsigned b, float c) {
    float d;
    asm("v_dot2_f32_bf16 %0, %1, %2, %3" : "=v"(d) : "v"(a), "v"(b), "v"(c));
    return d;
}

// ---------------------------------------------------------------------------
// scan: single 1024-thread block, counts -> start (exclusive), dinv
// ---------------------------------------------------------------------------
__global__ __launch_bounds__(1024) void k_scan(const int* __restrict__ counts,
                                               int* __restrict__ start,
                                               float* __restrict__ dinv, int n) {
    __shared__ int wsum[16];
    int tid = threadIdx.x;
    int lane = tid & 63, wvi = tid >> 6;
    int ipt = (n + 1023) >> 10;
    int c0 = tid * ipt;
    int c1 = min(n, c0 + ipt);
    if (c0 > n) c0 = n;
    int s = 0;
    for (int i = c0; i < c1; ++i) s += counts[i];
    int x = s;
#pragma unroll
    for (int off = 1; off < 64; off <<= 1) {
        int y = __shfl_up(x, off);
        if (lane >= off) x += y;
    }
    if (lane == 63) wsum[wvi] = x;
    __syncthreads();
    if (wvi == 0 && lane < 16) {
        int t2 = wsum[lane];
#pragma unroll
        for (int off = 1; off < 16; off <<= 1) {
            int y = __shfl_up(t2, off);
            if (lane >= off) t2 += y;
        }
        wsum[lane] = t2;
    }
    __syncthreads();
    int waveoff = (wvi > 0) ? wsum[wvi - 1] : 0;
    int run = waveoff + x - s;
    for (int i = c0; i < c1; ++i) {
        int v = counts[i];
        start[i] = run;
        dinv[i] = rsqrtf((float)(v + 1));  // +1 self-loop
        run += v;
    }
    if (tid == 0) start[n] = wsum[15];
}

// ---------------------------------------------------------------------------
// MFMA GEMM core: block = 64 nodes x 64 oc, 4 waves, wave w = 16-row strip.
// stage_w_bf16: consecutive lanes handle consecutive k -> LDS stores are
// stride-2B across lanes (2-way bank alias = free).  Global w read is
// strided but w is 16KB and L2-hot across all blocks.
// ---------------------------------------------------------------------------
__device__ __forceinline__ void stage_w_bf16(unsigned short* Wt,
                                             const float* __restrict__ w, int tid) {
    for (int idx = tid; idx < 1024; idx += 256) {
        int k = idx & 63, n4 = (idx >> 6) * 4;
        float4 wv = *(const float4*)&w[k * 64 + n4];
        Wt[(n4 + 0) * ALD + k] = f2bf(wv.x);
        Wt[(n4 + 1) * ALD + k] = f2bf(wv.y);
        Wt[(n4 + 2) * ALD + k] = f2bf(wv.z);
        Wt[(n4 + 3) * ALD + k] = f2bf(wv.w);
    }
}

__device__ __forceinline__ void mfma_step(const unsigned short* Alds,
                                          const unsigned short* Wt,
                                          int tid, f32x4 acc[4]) {
    int lane = tid & 63;
    int m0 = (tid >> 6) * 16;
    int c16 = lane & 15, quad = lane >> 4;
    const unsigned short* ar = &Alds[(m0 + c16) * ALD + quad * 8];
    bf16x8 a0 = *(const bf16x8*)ar;
    bf16x8 a1 = *(const bf16x8*)(ar + 32);
#pragma unroll
    for (int nt = 0; nt < 4; ++nt) {
        const unsigned short* br = &Wt[(nt * 16 + c16) * ALD + quad * 8];
        bf16x8 b0 = *(const bf16x8*)br;
        bf16x8 b1 = *(const bf16x8*)(br + 32);
        acc[nt] = __builtin_amdgcn_mfma_f32_16x16x32_bf16(a0, b0, acc[nt], 0, 0, 0);
        acc[nt] = __builtin_amdgcn_mfma_f32_16x16x32_bf16(a1, b1, acc[nt], 0, 0, 0);
    }
}

// bf16-src 64x64 GEMM tile body.  qd!=nullptr -> f32 q out; else bf16 kv out.
__device__ __forceinline__ void stage_tile_body(
    const unsigned short* __restrict__ src, const float* __restrict__ w,
    const float* __restrict__ b, float* __restrict__ qd,
    unsigned short* __restrict__ kvdst, int kv_stride, int kv_off, bool relu_in,
    int node0, int n, int tid, unsigned short* Alds, unsigned short* Wt) {
    stage_w_bf16(Wt, w, tid);
    for (int idx = tid; idx < 512; idx += 256) {
        int r = idx >> 3, seg = idx & 7;
        int node = node0 + r;
        uint4 u = make_uint4(0u, 0u, 0u, 0u);
        if (node < n) u = *(const uint4*)&src[(size_t)node * 64 + seg * 8];
        if (relu_in) {
            u.x = relu_pk(u.x); u.y = relu_pk(u.y);
            u.z = relu_pk(u.z); u.w = relu_pk(u.w);
        }
        *(uint4*)&Alds[r * ALD + seg * 8] = u;
    }
    __syncthreads();
    f32x4 acc[4];
#pragma unroll
    for (int nt = 0; nt < 4; ++nt) acc[nt] = (f32x4){0.f, 0.f, 0.f, 0.f};
    mfma_step(Alds, Wt, tid, acc);

    int lane = tid & 63;
    int m0 = (tid >> 6) * 16, c16 = lane & 15, quad = lane >> 4;
    float bias[4];
#pragma unroll
    for (int nt = 0; nt < 4; ++nt) bias[nt] = b[nt * 16 + c16];
    if (qd) {
#pragma unroll
        for (int i = 0; i < 4; ++i) {
            int node = node0 + m0 + quad * 4 + i;
            if (node < n) {
#pragma unroll
                for (int nt = 0; nt < 4; ++nt)
                    qd[(size_t)node * 64 + nt * 16 + c16] = acc[nt][i] + bias[nt];
            }
        }
    } else {
#pragma unroll
        for (int i = 0; i < 4; ++i) {
            int node = node0 + m0 + quad * 4 + i;
            if (node < n) {
#pragma unroll
                for (int nt = 0; nt < 4; ++nt)
                    kvdst[(size_t)node * kv_stride + kv_off + nt * 16 + c16] =
                        f2bf(acc[nt][i] + bias[nt]);
            }
        }
    }
}

// ---------------------------------------------------------------------------
// lin1 (+ fused layer-0 V GEMM) co-scheduled with degree counting:
//   blocks [0, NT):        h = relu(x@W1+b1) -> xs0;  V0 = h@Wv0+bv0 -> kv0
//   blocks [NT, NT+nsb):   atomic degree counts (independent; provides the
//                          co-resident waves that hide lin1's serial chain)
// ---------------------------------------------------------------------------
__global__ __launch_bounds__(256, 4) void k_lin1cnt(
    const float* __restrict__ x, const float* __restrict__ w,
    const float* __restrict__ b, const float* __restrict__ wv0,
    const float* __restrict__ bv0, unsigned short* __restrict__ h,
    unsigned short* __restrict__ kv, const int* __restrict__ ei,
    int* __restrict__ counts, int E, int n, int NT) {
    __shared__ __align__(16) unsigned short Alds[64 * ALD];
    __shared__ __align__(16) unsigned short Wt[64 * ALD];
    int tid = threadIdx.x;
    int bx = blockIdx.x;
    if (bx >= NT) {
        int e = (bx - NT) * 256 + tid;
        if (e < E) atomicAdd(&counts[ei[E + e]], 1);
        return;
    }
    int node0 = bx * 64;
    f32x4 acc[4];
#pragma unroll
    for (int nt = 0; nt < 4; ++nt) acc[nt] = (f32x4){0.f, 0.f, 0.f, 0.f};

    for (int kc = 0; kc < 256; kc += 64) {
        __syncthreads();
        stage_w_bf16(Wt, w + kc * 64, tid);
        for (int idx = tid; idx < 1024; idx += 256) {
            int r = idx >> 4, c4 = (idx & 15) * 4;
            int node = node0 + r;
            float4 v = make_float4(0.f, 0.f, 0.f, 0.f);
            if (node < n) v = *(const float4*)&x[(size_t)node * 256 + kc + c4];
            Alds[r * ALD + c4 + 0] = f2bf(v.x);
            Alds[r * ALD + c4 + 1] = f2bf(v.y);
            Alds[r * ALD + c4 + 2] = f2bf(v.z);
            Alds[r * ALD + c4 + 3] = f2bf(v.w);
        }
        __syncthreads();
        mfma_step(Alds, Wt, tid, acc);
    }
    int lane = tid & 63;
    int m0 = (tid >> 6) * 16, c16 = lane & 15, quad = lane >> 4;
    float bias[4];
#pragma unroll
    for (int nt = 0; nt < 4; ++nt) bias[nt] = b[nt * 16 + c16];

    __syncthreads();
    stage_w_bf16(Wt, wv0, tid);
#pragma unroll
    for (int i = 0; i < 4; ++i) {
        int row = m0 + quad * 4 + i;
        int node = node0 + row;
#pragma unroll
        for (int nt = 0; nt < 4; ++nt) {
            unsigned short hb = f2bf(fmaxf(acc[nt][i] + bias[nt], 0.f));
            Alds[row * ALD + nt * 16 + c16] = hb;
            if (node < n) h[(size_t)node * 64 + nt * 16 + c16] = hb;
        }
    }
    __syncthreads();
    f32x4 acc2[4];
#pragma unroll
    for (int nt = 0; nt < 4; ++nt) acc2[nt] = (f32x4){0.f, 0.f, 0.f, 0.f};
    mfma_step(Alds, Wt, tid, acc2);
    float bias2[4];
#pragma unroll
    for (int nt = 0; nt < 4; ++nt) bias2[nt] = bv0[nt * 16 + c16];
#pragma unroll
    for (int i = 0; i < 4; ++i) {
        int node = node0 + m0 + quad * 4 + i;
        if (node < n) {
#pragma unroll
            for (int nt = 0; nt < 4; ++nt)
                kv[(size_t)node * 64 + nt * 16 + c16] = f2bf(acc2[nt][i] + bias2[nt]);
        }
    }
}

// ---------------------------------------------------------------------------
// scatter fused with the 4 slice-0 K/V staging GEMMs.
//   blocks [0, nsb):          CSR scatter (consumes counts via atomicSub)
//   blocks [nsb, nsb+4*NT):   j = (bx-nsb)/NT: {L1K,L1V,L2K,L2V} x s0
// ---------------------------------------------------------------------------
__global__ __launch_bounds__(256, 4) void k_scatter_stage(
    const int* __restrict__ ei, const int* __restrict__ startA,
    int* __restrict__ counts, unsigned short* __restrict__ ebuf, int E, int nsb,
    const unsigned short* __restrict__ xs,
    const float* __restrict__ wk, const float* __restrict__ bk,
    const float* __restrict__ wv, const float* __restrict__ bv,
    unsigned short* __restrict__ kv1, unsigned short* __restrict__ kv2,
    int n, int NT) {
    __shared__ __align__(16) unsigned short Alds[64 * ALD];
    __shared__ __align__(16) unsigned short Wt[64 * ALD];
    int bx = blockIdx.x;
    if (bx < nsb) {
        int e = bx * 256 + threadIdx.x;
        if (e < E) {
            int r = ei[e], c = ei[E + e];
            int pos = startA[c] + atomicSub(&counts[c], 1) - 1;
            ebuf[pos] = (unsigned short)r;
        }
        return;
    }
    int t = bx - nsb;
    int j = t / NT, tile = t - j * NT;
    int layer = 1 + (j >> 1), isV = j & 1;
    const float* w = (isV ? wv : wk) + layer * 4096;
    const float* b = (isV ? bv : bk) + layer * 64;
    unsigned short* dst = (layer == 1) ? kv1 : kv2;
    int stride = (layer == 1) ? 256 : 384;
    int koff = isV ? 64 : 0;
    stage_tile_body(xs, w, b, nullptr, dst, stride, koff, false,
                    tile * 64, n, threadIdx.x, Alds, Wt);
}

// ---------------------------------------------------------------------------
// staging launches between attention layers.
//  phase 1 (5 jobs): {L1K,L1V,L2K,L2V} x s1  +  q(layer1, src s1)
//  phase 2 (3 jobs): {L2K,L2V} x s2          +  q(layer2, src s2)
// ---------------------------------------------------------------------------
__global__ __launch_bounds__(256, 4) void k_stage(
    const unsigned short* __restrict__ xs, size_t sstride,
    const float* __restrict__ wq, const float* __restrict__ bq,
    const float* __restrict__ wk, const float* __restrict__ bk,
    const float* __restrict__ wv, const float* __restrict__ bv,
    float* __restrict__ qbuf, unsigned short* __restrict__ kv1,
    unsigned short* __restrict__ kv2, int n, int phase) {
    __shared__ __align__(16) unsigned short Alds[64 * ALD];
    __shared__ __align__(16) unsigned short Wt[64 * ALD];
    int j = blockIdx.y;
    int layer, s, isV = 0, isQ = 0;
    if (phase == 1) {
        if (j < 4) { layer = 1 + (j >> 1); isV = j & 1; s = 1; }
        else       { layer = 1; isQ = 1; s = 1; }
    } else {
        if (j < 2) { layer = 2; isV = j; s = 2; }
        else       { layer = 2; isQ = 1; s = 2; }
    }
    const unsigned short* src = xs + (size_t)s * sstride;
    const float* w; const float* b;
    float* qd = nullptr; unsigned short* dst = nullptr;
    int stride = 0, koff = 0;
    if (isQ) {
        w = wq + layer * 4096; b = bq + layer * 64; qd = qbuf;
    } else {
        w = (isV ? wv : wk) + layer * 4096;
        b = (isV ? bv : bk) + layer * 64;
        dst = (layer == 1) ? kv1 : kv2;
        stride = (layer == 1) ? 256 : 384;
        koff = s * 128 + (isV ? 64 : 0);
    }
    stage_tile_body(src, w, b, qd, dst, stride, koff, true,
                    blockIdx.x * 64, n, threadIdx.x, Alds, Wt);
}

// ---------------------------------------------------------------------------
// attention + aggregate, CSR by destination.  One wave per node.
// Lane = (edge-slot g = lane>>3, head h = lane&7): 8 edges in flight,
// lane-local dot/softmax (compiler-scheduled).  q from precomputed f32
// buffer, packed to bf16 pairs for v_dot2_f32_bf16 K-dots.
// T==1: pure dinv-weighted V gather.  FINAL: fused W2 + log_softmax.
// ---------------------------------------------------------------------------
template <int T, bool FINAL>
__global__ __launch_bounds__(256) void k_attn(
    const int* __restrict__ start, const unsigned short* __restrict__ ebuf,
    const float* __restrict__ dinv, const float* __restrict__ q,
    const unsigned short* __restrict__ kv,
    const float* __restrict__ w2, const float* __restrict__ b2,
    unsigned short* __restrict__ outb, float* __restrict__ outf, int n) {
    const int KVS = (T == 1) ? 64 : T * 128;
    int node = (int)((blockIdx.x * (size_t)blockDim.x + threadIdx.x) >> 6);
    int lane = threadIdx.x & 63;
    if (node >= n) return;
    int g = lane >> 3;
    int cb = (lane & 7) * 8;

    unsigned qpk[4];
    if (T > 1) {
        const float isd = 0.35355339059327373f;  // 1/sqrt(8)
        float4 q0 = *(const float4*)&q[(size_t)node * 64 + cb];
        float4 q1 = *(const float4*)&q[(size_t)node * 64 + cb + 4];
        qpk[0] = ((unsigned)f2bf(q0.y * isd) << 16) | (unsigned)f2bf(q0.x * isd);
        qpk[1] = ((unsigned)f2bf(q0.w * isd) << 16) | (unsigned)f2bf(q0.z * isd);
        qpk[2] = ((unsigned)f2bf(q1.y * isd) << 16) | (unsigned)f2bf(q1.x * isd);
        qpk[3] = ((unsigned)f2bf(q1.w * isd) << 16) | (unsigned)f2bf(q1.z * isd);
    }
    float dc = dinv[node];
    int s0 = start[node];
    int cnt = start[node + 1] - s0 + 1;

    float acc[8];
#pragma unroll
    for (int k = 0; k < 8; ++k) acc[k] = 0.f;

    for (int base = 0; base < cnt; base += 8) {
        int idx = base + g;
        bool valid = idx < cnt;
        int r = node;
        if (valid && idx > 0) r = ebuf[s0 + idx - 1];
        float dr = valid ? dinv[r] : 0.f;
        const unsigned short* rkv = kv + (size_t)r * KVS;

        float cf[T];
        if (T > 1) {
            float sc[T];
            float m = -1e30f;
#pragma unroll
            for (int s = 0; s < T; ++s) {
                uint4 ku = *(const uint4*)&rkv[s * 128 + cb];
                float p = dot2bf(qpk[3], ku.w,
                          dot2bf(qpk[2], ku.z,
                          dot2bf(qpk[1], ku.y,
                          dot2bf(qpk[0], ku.x, 0.f))));
                sc[s] = p;
                m = fmaxf(m, p);
            }
            float denom = 0.f;
#pragma unroll
            for (int s = 0; s < T; ++s) { sc[s] = __expf(sc[s] - m); denom += sc[s]; }
            float w = dr / denom;
#pragma unroll
            for (int s = 0; s < T; ++s) cf[s] = w * sc[s];
        } else {
            cf[0] = dr;
        }
#pragma unroll
        for (int s = 0; s < T; ++s) {
            uint4 vu = *(const uint4*)&rkv[((T == 1) ? 0 : s * 128 + 64) + cb];
            float wv_ = cf[s];
            acc[0] += wv_ * bflo(vu.x); acc[1] += wv_ * bfhi(vu.x);
            acc[2] += wv_ * bflo(vu.y); acc[3] += wv_ * bfhi(vu.y);
            acc[4] += wv_ * bflo(vu.z); acc[5] += wv_ * bfhi(vu.z);
            acc[6] += wv_ * bflo(vu.w); acc[7] += wv_ * bfhi(vu.w);
        }
    }

#pragma unroll
    for (int off = 8; off < 64; off <<= 1) {
#pragma unroll
        for (int k = 0; k < 8; ++k) acc[k] += __shfl_xor(acc[k], off);
    }

    if (!FINAL) {
        if (g == 0) {
            ushort4 o0, o1;
            o0.x = f2bf(acc[0] * dc); o0.y = f2bf(acc[1] * dc);
            o0.z = f2bf(acc[2] * dc); o0.w = f2bf(acc[3] * dc);
            o1.x = f2bf(acc[4] * dc); o1.y = f2bf(acc[5] * dc);
            o1.z = f2bf(acc[6] * dc); o1.w = f2bf(acc[7] * dc);
            *(ushort4*)&outb[(size_t)node * 64 + cb] = o0;
            *(ushort4*)&outb[(size_t)node * 64 + cb + 4] = o1;
        }
    } else {
        // every lane holds the full row: channel c on lane (c>>3), reg acc[c&7]
        float lg = b2[lane];
#pragma unroll
        for (int c = 0; c < 64; ++c) {
            float xc = fmaxf(__shfl(acc[c & 7], c >> 3) * dc, 0.f);
            lg += xc * w2[c * 64 + lane];
        }
        float mx = lg;
#pragma unroll
        for (int off = 1; off < 64; off <<= 1) mx = fmaxf(mx, __shfl_xor(mx, off));
        float e = __expf(lg - mx);
        float ssum = e;
#pragma unroll
        for (int off = 1; off < 64; off <<= 1) ssum += __shfl_xor(ssum, off);
        outf[(size_t)node * 64 + lane] = lg - mx - __logf(ssum);
    }
}

// ---------------------------------------------------------------------------
extern "C" void kernel_launch(void* const* d_in, const int* in_sizes, int n_in,
                              void* d_out, int out_size, void* d_ws, size_t ws_size,
                              hipStream_t stream) {
    const float* x  = (const float*)d_in[0];
    const int*   ei = (const int*)d_in[1];
    const float* w1 = (const float*)d_in[2];
    const float* b1 = (const float*)d_in[3];
    const float* wq = (const float*)d_in[4];
    const float* bq = (const float*)d_in[5];
    const float* wk = (const float*)d_in[6];
    const float* bk = (const float*)d_in[7];
    const float* wv = (const float*)d_in[8];
    const float* bv = (const float*)d_in[9];
    const float* w2 = (const float*)d_in[10];
    const float* b2 = (const float*)d_in[11];
    float* outp = (float*)d_out;

    int n = in_sizes[0] / 256;
    int E = in_sizes[1] / 2;

    float* ws = (float*)d_ws;
    size_t off = 0;
    float* dinv = ws + off; off += (size_t)n;
    float* qbuf = ws + off; off += (size_t)n * 64;
    unsigned short* xsU = (unsigned short*)(ws + off); off += (size_t)n * 96;   // 3 slices bf16
    unsigned short* kv0 = (unsigned short*)(ws + off); off += (size_t)n * 32;   // n*64 bf16
    unsigned short* kv1 = (unsigned short*)(ws + off); off += (size_t)n * 128;  // n*256 bf16
    unsigned short* kv2 = (unsigned short*)(ws + off); off += (size_t)n * 192;  // n*384 bf16
    int* wsI    = (int*)(ws + off);
    int* counts = wsI;                      // n
    int* startA = wsI + n;                  // n+1
    unsigned short* ebuf = (unsigned short*)(wsI + 2 * n + 1);  // E u16

    size_t sstride = (size_t)n * 64;
    int NT = (n + 63) / 64;
    int nsb = (E + 255) / 256;
    int attn_grid = (int)(((size_t)n * 64 + 255) / 256);

    // 1. zero counts
    hipMemsetAsync(counts, 0, (size_t)n * sizeof(int), stream);
    // 2. lin1 (+V0 GEMM)  ||  degree counts (co-resident occupancy)
    k_lin1cnt<<<NT + nsb, 256, 0, stream>>>(x, w1, b1, wv, bv, xsU, kv0,
                                            ei, counts, E, n, NT);
    // 3. scan
    k_scan<<<1, 1024, 0, stream>>>(counts, startA, dinv, n);
    // 4. scatter  ||  slice-0 K/V staging (4 jobs)
    k_scatter_stage<<<nsb + 4 * NT, 256, 0, stream>>>(
        ei, startA, counts, ebuf, E, nsb, xsU, wk, bk, wv, bv, kv1, kv2, n, NT);
    // 5. layer 0 attention (T=1) -> xs slice 1
    k_attn<1, false><<<attn_grid, 256, 0, stream>>>(
        startA, ebuf, dinv, nullptr, kv0, nullptr, nullptr,
        xsU + sstride, nullptr, n);
    // 6. slice-1 K/V staging + q1 (5 jobs)
    {
        dim3 grid(NT, 5);
        k_stage<<<grid, 256, 0, stream>>>(xsU, sstride, wq, bq, wk, bk, wv, bv,
                                          qbuf, kv1, kv2, n, 1);
    }
    // 7. layer 1 attention (T=2) -> xs slice 2
    k_attn<2, false><<<attn_grid, 256, 0, stream>>>(
        startA, ebuf, dinv, qbuf, kv1, nullptr, nullptr,
        xsU + 2 * sstride, nullptr, n);
    // 8. slice-2 K/V staging + q2 (3 jobs)
    {
        dim3 grid(NT, 3);
        k_stage<<<grid, 256, 0, stream>>>(xsU, sstride, wq, bq, wk, bk, wv, bv,
                                          qbuf, kv1, kv2, n, 2);
    }
    // 9. layer 2 attention (T=3) + final projection + log_softmax
    k_attn<3, true><<<attn_grid, 256, 0, stream>>>(
        startA, ebuf, dinv, qbuf, kv2, w2, b2, nullptr, outp, n);
}

// Round 8
// 257.565 us; speedup vs baseline: 1.0055x; 1.0055x over previous
//
#include <hip/hip_runtime.h>
#include <math.h>

#define HID 64
#define HEADS 8
#define ALD 72

typedef __attribute__((ext_vector_type(8))) short bf16x8;
typedef __attribute__((ext_vector_type(4))) float f32x4;

// ---------------------------------------------------------------------------
// bf16 helpers (storage compression; accumulation stays f32)
// ---------------------------------------------------------------------------
__device__ __forceinline__ unsigned short f2bf(float f) {
    union { float f; unsigned int u; } cv; cv.f = f;
    unsigned int u = cv.u;
    unsigned int r = (u + 0x7FFFu + ((u >> 16) & 1u)) >> 16;  // RNE
    return (unsigned short)r;
}
__device__ __forceinline__ float bflo(unsigned int u) {
    union { unsigned int u; float f; } cv; cv.u = u << 16; return cv.f;
}
__device__ __forceinline__ float bfhi(unsigned int u) {
    union { unsigned int u; float f; } cv; cv.u = u & 0xFFFF0000u; return cv.f;
}
__device__ __forceinline__ unsigned relu_pk(unsigned u) {  // relu on 2 packed bf16
    unsigned m = ((u & 0x8000u) ? 0u : 0xFFFFu) |
                 ((u & 0x80000000u) ? 0u : 0xFFFF0000u);
    return u & m;
}

// packed bf16-pair dot with f32 accumulate: d = a.lo*b.lo + a.hi*b.hi + c
__device__ __forceinline__ float dot2bf(unsigned a, unsigned b, float c) {
    float d;
    asm("v_dot2_f32_bf16 %0, %1, %2, %3" : "=v"(d) : "v"(a), "v"(b), "v"(c));
    return d;
}

// ---------------------------------------------------------------------------
// scan: single 1024-thread block, counts -> start (exclusive), dinv
// ---------------------------------------------------------------------------
__global__ __launch_bounds__(1024) void k_scan(const int* __restrict__ counts,
                                               int* __restrict__ start,
                                               float* __restrict__ dinv, int n) {
    __shared__ int wsum[16];
    int tid = threadIdx.x;
    int lane = tid & 63, wvi = tid >> 6;
    int ipt = (n + 1023) >> 10;
    int c0 = tid * ipt;
    int c1 = min(n, c0 + ipt);
    if (c0 > n) c0 = n;
    int s = 0;
    for (int i = c0; i < c1; ++i) s += counts[i];
    int x = s;
#pragma unroll
    for (int off = 1; off < 64; off <<= 1) {
        int y = __shfl_up(x, off);
        if (lane >= off) x += y;
    }
    if (lane == 63) wsum[wvi] = x;
    __syncthreads();
    if (wvi == 0 && lane < 16) {
        int t2 = wsum[lane];
#pragma unroll
        for (int off = 1; off < 16; off <<= 1) {
            int y = __shfl_up(t2, off);
            if (lane >= off) t2 += y;
        }
        wsum[lane] = t2;
    }
    __syncthreads();
    int waveoff = (wvi > 0) ? wsum[wvi - 1] : 0;
    int run = waveoff + x - s;
    for (int i = c0; i < c1; ++i) {
        int v = counts[i];
        start[i] = run;
        dinv[i] = rsqrtf((float)(v + 1));  // +1 self-loop
        run += v;
    }
    if (tid == 0) start[n] = wsum[15];
}

// ---------------------------------------------------------------------------
// MFMA GEMM core: block = 64 nodes x 64 oc, 4 waves, wave w = 16-row strip.
// stage_w_bf16: coalesced float4 global read (R0/R6 layout); the transposed
// LDS stores alias 2-way across banks which is free on CDNA4.
// ---------------------------------------------------------------------------
__device__ __forceinline__ void stage_w_bf16(unsigned short* Wt,
                                             const float* __restrict__ w, int tid) {
    for (int idx = tid; idx < 1024; idx += 256) {
        int k = idx >> 4, n4 = (idx & 15) * 4;
        float4 wv = *(const float4*)&w[k * 64 + n4];
        Wt[(n4 + 0) * ALD + k] = f2bf(wv.x);
        Wt[(n4 + 1) * ALD + k] = f2bf(wv.y);
        Wt[(n4 + 2) * ALD + k] = f2bf(wv.z);
        Wt[(n4 + 3) * ALD + k] = f2bf(wv.w);
    }
}

__device__ __forceinline__ void mfma_step(const unsigned short* Alds,
                                          const unsigned short* Wt,
                                          int tid, f32x4 acc[4]) {
    int lane = tid & 63;
    int m0 = (tid >> 6) * 16;
    int c16 = lane & 15, quad = lane >> 4;
    const unsigned short* ar = &Alds[(m0 + c16) * ALD + quad * 8];
    bf16x8 a0 = *(const bf16x8*)ar;
    bf16x8 a1 = *(const bf16x8*)(ar + 32);
#pragma unroll
    for (int nt = 0; nt < 4; ++nt) {
        const unsigned short* br = &Wt[(nt * 16 + c16) * ALD + quad * 8];
        bf16x8 b0 = *(const bf16x8*)br;
        bf16x8 b1 = *(const bf16x8*)(br + 32);
        acc[nt] = __builtin_amdgcn_mfma_f32_16x16x32_bf16(a0, b0, acc[nt], 0, 0, 0);
        acc[nt] = __builtin_amdgcn_mfma_f32_16x16x32_bf16(a1, b1, acc[nt], 0, 0, 0);
    }
}

// bf16-src 64x64 GEMM tile body.  qd!=nullptr -> f32 q out; else bf16 kv out.
__device__ __forceinline__ void stage_tile_body(
    const unsigned short* __restrict__ src, const float* __restrict__ w,
    const float* __restrict__ b, float* __restrict__ qd,
    unsigned short* __restrict__ kvdst, int kv_stride, int kv_off, bool relu_in,
    int node0, int n, int tid, unsigned short* Alds, unsigned short* Wt) {
    stage_w_bf16(Wt, w, tid);
    for (int idx = tid; idx < 512; idx += 256) {
        int r = idx >> 3, seg = idx & 7;
        int node = node0 + r;
        uint4 u = make_uint4(0u, 0u, 0u, 0u);
        if (node < n) u = *(const uint4*)&src[(size_t)node * 64 + seg * 8];
        if (relu_in) {
            u.x = relu_pk(u.x); u.y = relu_pk(u.y);
            u.z = relu_pk(u.z); u.w = relu_pk(u.w);
        }
        *(uint4*)&Alds[r * ALD + seg * 8] = u;
    }
    __syncthreads();
    f32x4 acc[4];
#pragma unroll
    for (int nt = 0; nt < 4; ++nt) acc[nt] = (f32x4){0.f, 0.f, 0.f, 0.f};
    mfma_step(Alds, Wt, tid, acc);

    int lane = tid & 63;
    int m0 = (tid >> 6) * 16, c16 = lane & 15, quad = lane >> 4;
    float bias[4];
#pragma unroll
    for (int nt = 0; nt < 4; ++nt) bias[nt] = b[nt * 16 + c16];
    if (qd) {
#pragma unroll
        for (int i = 0; i < 4; ++i) {
            int node = node0 + m0 + quad * 4 + i;
            if (node < n) {
#pragma unroll
                for (int nt = 0; nt < 4; ++nt)
                    qd[(size_t)node * 64 + nt * 16 + c16] = acc[nt][i] + bias[nt];
            }
        }
    } else {
#pragma unroll
        for (int i = 0; i < 4; ++i) {
            int node = node0 + m0 + quad * 4 + i;
            if (node < n) {
#pragma unroll
                for (int nt = 0; nt < 4; ++nt)
                    kvdst[(size_t)node * kv_stride + kv_off + nt * 16 + c16] =
                        f2bf(acc[nt][i] + bias[nt]);
            }
        }
    }
}

// ---------------------------------------------------------------------------
// lin1 (+ fused layer-0 V GEMM) co-scheduled with degree counting:
//   blocks [0, NT):        h = relu(x@W1+b1) -> xs0;  V0 = h@Wv0+bv0 -> kv0
//   blocks [NT, NT+nsb):   atomic degree counts (co-resident occupancy)
// ---------------------------------------------------------------------------
__global__ __launch_bounds__(256, 4) void k_lin1cnt(
    const float* __restrict__ x, const float* __restrict__ w,
    const float* __restrict__ b, const float* __restrict__ wv0,
    const float* __restrict__ bv0, unsigned short* __restrict__ h,
    unsigned short* __restrict__ kv, const int* __restrict__ ei,
    int* __restrict__ counts, int E, int n, int NT) {
    __shared__ __align__(16) unsigned short Alds[64 * ALD];
    __shared__ __align__(16) unsigned short Wt[64 * ALD];
    int tid = threadIdx.x;
    int bx = blockIdx.x;
    if (bx >= NT) {
        int e = (bx - NT) * 256 + tid;
        if (e < E) atomicAdd(&counts[ei[E + e]], 1);
        return;
    }
    int node0 = bx * 64;
    f32x4 acc[4];
#pragma unroll
    for (int nt = 0; nt < 4; ++nt) acc[nt] = (f32x4){0.f, 0.f, 0.f, 0.f};

    for (int kc = 0; kc < 256; kc += 64) {
        __syncthreads();
        stage_w_bf16(Wt, w + kc * 64, tid);
        for (int idx = tid; idx < 1024; idx += 256) {
            int r = idx >> 4, c4 = (idx & 15) * 4;
            int node = node0 + r;
            float4 v = make_float4(0.f, 0.f, 0.f, 0.f);
            if (node < n) v = *(const float4*)&x[(size_t)node * 256 + kc + c4];
            Alds[r * ALD + c4 + 0] = f2bf(v.x);
            Alds[r * ALD + c4 + 1] = f2bf(v.y);
            Alds[r * ALD + c4 + 2] = f2bf(v.z);
            Alds[r * ALD + c4 + 3] = f2bf(v.w);
        }
        __syncthreads();
        mfma_step(Alds, Wt, tid, acc);
    }
    int lane = tid & 63;
    int m0 = (tid >> 6) * 16, c16 = lane & 15, quad = lane >> 4;
    float bias[4];
#pragma unroll
    for (int nt = 0; nt < 4; ++nt) bias[nt] = b[nt * 16 + c16];

    __syncthreads();
    stage_w_bf16(Wt, wv0, tid);
#pragma unroll
    for (int i = 0; i < 4; ++i) {
        int row = m0 + quad * 4 + i;
        int node = node0 + row;
#pragma unroll
        for (int nt = 0; nt < 4; ++nt) {
            unsigned short hb = f2bf(fmaxf(acc[nt][i] + bias[nt], 0.f));
            Alds[row * ALD + nt * 16 + c16] = hb;
            if (node < n) h[(size_t)node * 64 + nt * 16 + c16] = hb;
        }
    }
    __syncthreads();
    f32x4 acc2[4];
#pragma unroll
    for (int nt = 0; nt < 4; ++nt) acc2[nt] = (f32x4){0.f, 0.f, 0.f, 0.f};
    mfma_step(Alds, Wt, tid, acc2);
    float bias2[4];
#pragma unroll
    for (int nt = 0; nt < 4; ++nt) bias2[nt] = bv0[nt * 16 + c16];
#pragma unroll
    for (int i = 0; i < 4; ++i) {
        int node = node0 + m0 + quad * 4 + i;
        if (node < n) {
#pragma unroll
            for (int nt = 0; nt < 4; ++nt)
                kv[(size_t)node * 64 + nt * 16 + c16] = f2bf(acc2[nt][i] + bias2[nt]);
        }
    }
}

// ---------------------------------------------------------------------------
// scatter fused with the 4 slice-0 K/V staging GEMMs.
//   blocks [0, nsb):          CSR scatter (consumes counts via atomicSub)
//   blocks [nsb, nsb+4*NT):   j = (bx-nsb)/NT: {L1K,L1V,L2K,L2V} x s0
// ---------------------------------------------------------------------------
__global__ __launch_bounds__(256, 4) void k_scatter_stage(
    const int* __restrict__ ei, const int* __restrict__ startA,
    int* __restrict__ counts, unsigned short* __restrict__ ebuf, int E, int nsb,
    const unsigned short* __restrict__ xs,
    const float* __restrict__ wk, const float* __restrict__ bk,
    const float* __restrict__ wv, const float* __restrict__ bv,
    unsigned short* __restrict__ kv1, unsigned short* __restrict__ kv2,
    int n, int NT) {
    __shared__ __align__(16) unsigned short Alds[64 * ALD];
    __shared__ __align__(16) unsigned short Wt[64 * ALD];
    int bx = blockIdx.x;
    if (bx < nsb) {
        int e = bx * 256 + threadIdx.x;
        if (e < E) {
            int r = ei[e], c = ei[E + e];
            int pos = startA[c] + atomicSub(&counts[c], 1) - 1;
            ebuf[pos] = (unsigned short)r;
        }
        return;
    }
    int t = bx - nsb;
    int j = t / NT, tile = t - j * NT;
    int layer = 1 + (j >> 1), isV = j & 1;
    const float* w = (isV ? wv : wk) + layer * 4096;
    const float* b = (isV ? bv : bk) + layer * 64;
    unsigned short* dst = (layer == 1) ? kv1 : kv2;
    int stride = (layer == 1) ? 256 : 384;
    int koff = isV ? 64 : 0;
    stage_tile_body(xs, w, b, nullptr, dst, stride, koff, false,
                    tile * 64, n, threadIdx.x, Alds, Wt);
}

// ---------------------------------------------------------------------------
// staging launches between attention layers.
//  phase 1 (5 jobs): {L1K,L1V,L2K,L2V} x s1  +  q(layer1, src s1)
//  phase 2 (3 jobs): {L2K,L2V} x s2          +  q(layer2, src s2)
// ---------------------------------------------------------------------------
__global__ __launch_bounds__(256, 4) void k_stage(
    const unsigned short* __restrict__ xs, size_t sstride,
    const float* __restrict__ wq, const float* __restrict__ bq,
    const float* __restrict__ wk, const float* __restrict__ bk,
    const float* __restrict__ wv, const float* __restrict__ bv,
    float* __restrict__ qbuf, unsigned short* __restrict__ kv1,
    unsigned short* __restrict__ kv2, int n, int phase) {
    __shared__ __align__(16) unsigned short Alds[64 * ALD];
    __shared__ __align__(16) unsigned short Wt[64 * ALD];
    int j = blockIdx.y;
    int layer, s, isV = 0, isQ = 0;
    if (phase == 1) {
        if (j < 4) { layer = 1 + (j >> 1); isV = j & 1; s = 1; }
        else       { layer = 1; isQ = 1; s = 1; }
    } else {
        if (j < 2) { layer = 2; isV = j; s = 2; }
        else       { layer = 2; isQ = 1; s = 2; }
    }
    const unsigned short* src = xs + (size_t)s * sstride;
    const float* w; const float* b;
    float* qd = nullptr; unsigned short* dst = nullptr;
    int stride = 0, koff = 0;
    if (isQ) {
        w = wq + layer * 4096; b = bq + layer * 64; qd = qbuf;
    } else {
        w = (isV ? wv : wk) + layer * 4096;
        b = (isV ? bv : bk) + layer * 64;
        dst = (layer == 1) ? kv1 : kv2;
        stride = (layer == 1) ? 256 : 384;
        koff = s * 128 + (isV ? 64 : 0);
    }
    stage_tile_body(src, w, b, qd, dst, stride, koff, true,
                    blockIdx.x * 64, n, threadIdx.x, Alds, Wt);
}

// ---------------------------------------------------------------------------
// attention + aggregate, CSR by destination.  One wave per node.
// Lane = (edge-slot g = lane>>3, head h = lane&7): 8 edges in flight,
// lane-local dot/softmax.  Edge-chunk loop unrolled 2x so the compiler
// issues two chunks' ebuf/dinv/K/V loads together (2x memory-level
// parallelism, compiler-scheduled — no manual rotation/pinning).
// q from precomputed f32 buffer, packed bf16 pairs for v_dot2_f32_bf16.
// T==1: pure dinv-weighted V gather.  FINAL: fused W2 + log_softmax.
// ---------------------------------------------------------------------------
template <int T, bool FINAL>
__global__ __launch_bounds__(256) void k_attn(
    const int* __restrict__ start, const unsigned short* __restrict__ ebuf,
    const float* __restrict__ dinv, const float* __restrict__ q,
    const unsigned short* __restrict__ kv,
    const float* __restrict__ w2, const float* __restrict__ b2,
    unsigned short* __restrict__ outb, float* __restrict__ outf, int n) {
    const int KVS = (T == 1) ? 64 : T * 128;
    int node = (int)((blockIdx.x * (size_t)blockDim.x + threadIdx.x) >> 6);
    int lane = threadIdx.x & 63;
    if (node >= n) return;
    int g = lane >> 3;
    int cb = (lane & 7) * 8;

    unsigned qpk[4];
    if (T > 1) {
        const float isd = 0.35355339059327373f;  // 1/sqrt(8)
        float4 q0 = *(const float4*)&q[(size_t)node * 64 + cb];
        float4 q1 = *(const float4*)&q[(size_t)node * 64 + cb + 4];
        qpk[0] = ((unsigned)f2bf(q0.y * isd) << 16) | (unsigned)f2bf(q0.x * isd);
        qpk[1] = ((unsigned)f2bf(q0.w * isd) << 16) | (unsigned)f2bf(q0.z * isd);
        qpk[2] = ((unsigned)f2bf(q1.y * isd) << 16) | (unsigned)f2bf(q1.x * isd);
        qpk[3] = ((unsigned)f2bf(q1.w * isd) << 16) | (unsigned)f2bf(q1.z * isd);
    }
    float dc = dinv[node];
    int s0 = start[node];
    int cnt = start[node + 1] - s0 + 1;

    float acc[8];
#pragma unroll
    for (int k = 0; k < 8; ++k) acc[k] = 0.f;

#pragma unroll 2
    for (int base = 0; base < cnt; base += 8) {
        int idx = base + g;
        bool valid = idx < cnt;
        int r = node;
        if (valid && idx > 0) r = ebuf[s0 + idx - 1];
        float dr = valid ? dinv[r] : 0.f;
        const unsigned short* rkv = kv + (size_t)r * KVS;

        float cf[T];
        if (T > 1) {
            float sc[T];
            float m = -1e30f;
#pragma unroll
            for (int s = 0; s < T; ++s) {
                uint4 ku = *(const uint4*)&rkv[s * 128 + cb];
                float p = dot2bf(qpk[3], ku.w,
                          dot2bf(qpk[2], ku.z,
                          dot2bf(qpk[1], ku.y,
                          dot2bf(qpk[0], ku.x, 0.f))));
                sc[s] = p;
                m = fmaxf(m, p);
            }
            float denom = 0.f;
#pragma unroll
            for (int s = 0; s < T; ++s) { sc[s] = __expf(sc[s] - m); denom += sc[s]; }
            float w = dr / denom;
#pragma unroll
            for (int s = 0; s < T; ++s) cf[s] = w * sc[s];
        } else {
            cf[0] = dr;
        }
#pragma unroll
        for (int s = 0; s < T; ++s) {
            uint4 vu = *(const uint4*)&rkv[((T == 1) ? 0 : s * 128 + 64) + cb];
            float wv_ = cf[s];
            acc[0] += wv_ * bflo(vu.x); acc[1] += wv_ * bfhi(vu.x);
            acc[2] += wv_ * bflo(vu.y); acc[3] += wv_ * bfhi(vu.y);
            acc[4] += wv_ * bflo(vu.z); acc[5] += wv_ * bfhi(vu.z);
            acc[6] += wv_ * bflo(vu.w); acc[7] += wv_ * bfhi(vu.w);
        }
    }

#pragma unroll
    for (int off = 8; off < 64; off <<= 1) {
#pragma unroll
        for (int k = 0; k < 8; ++k) acc[k] += __shfl_xor(acc[k], off);
    }

    if (!FINAL) {
        if (g == 0) {
            ushort4 o0, o1;
            o0.x = f2bf(acc[0] * dc); o0.y = f2bf(acc[1] * dc);
            o0.z = f2bf(acc[2] * dc); o0.w = f2bf(acc[3] * dc);
            o1.x = f2bf(acc[4] * dc); o1.y = f2bf(acc[5] * dc);
            o1.z = f2bf(acc[6] * dc); o1.w = f2bf(acc[7] * dc);
            *(ushort4*)&outb[(size_t)node * 64 + cb] = o0;
            *(ushort4*)&outb[(size_t)node * 64 + cb + 4] = o1;
        }
    } else {
        // every lane holds the full row: channel c on lane (c>>3), reg acc[c&7]
        float lg = b2[lane];
#pragma unroll
        for (int c = 0; c < 64; ++c) {
            float xc = fmaxf(__shfl(acc[c & 7], c >> 3) * dc, 0.f);
            lg += xc * w2[c * 64 + lane];
        }
        float mx = lg;
#pragma unroll
        for (int off = 1; off < 64; off <<= 1) mx = fmaxf(mx, __shfl_xor(mx, off));
        float e = __expf(lg - mx);
        float ssum = e;
#pragma unroll
        for (int off = 1; off < 64; off <<= 1) ssum += __shfl_xor(ssum, off);
        outf[(size_t)node * 64 + lane] = lg - mx - __logf(ssum);
    }
}

// ---------------------------------------------------------------------------
extern "C" void kernel_launch(void* const* d_in, const int* in_sizes, int n_in,
                              void* d_out, int out_size, void* d_ws, size_t ws_size,
                              hipStream_t stream) {
    const float* x  = (const float*)d_in[0];
    const int*   ei = (const int*)d_in[1];
    const float* w1 = (const float*)d_in[2];
    const float* b1 = (const float*)d_in[3];
    const float* wq = (const float*)d_in[4];
    const float* bq = (const float*)d_in[5];
    const float* wk = (const float*)d_in[6];
    const float* bk = (const float*)d_in[7];
    const float* wv = (const float*)d_in[8];
    const float* bv = (const float*)d_in[9];
    const float* w2 = (const float*)d_in[10];
    const float* b2 = (const float*)d_in[11];
    float* outp = (float*)d_out;

    int n = in_sizes[0] / 256;
    int E = in_sizes[1] / 2;

    float* ws = (float*)d_ws;
    size_t off = 0;
    float* dinv = ws + off; off += (size_t)n;
    float* qbuf = ws + off; off += (size_t)n * 64;
    unsigned short* xsU = (unsigned short*)(ws + off); off += (size_t)n * 96;   // 3 slices bf16
    unsigned short* kv0 = (unsigned short*)(ws + off); off += (size_t)n * 32;   // n*64 bf16
    unsigned short* kv1 = (unsigned short*)(ws + off); off += (size_t)n * 128;  // n*256 bf16
    unsigned short* kv2 = (unsigned short*)(ws + off); off += (size_t)n * 192;  // n*384 bf16
    int* wsI    = (int*)(ws + off);
    int* counts = wsI;                      // n
    int* startA = wsI + n;                  // n+1
    unsigned short* ebuf = (unsigned short*)(wsI + 2 * n + 1);  // E u16

    size_t sstride = (size_t)n * 64;
    int NT = (n + 63) / 64;
    int nsb = (E + 255) / 256;
    int attn_grid = (int)(((size_t)n * 64 + 255) / 256);

    // 1. zero counts
    hipMemsetAsync(counts, 0, (size_t)n * sizeof(int), stream);
    // 2. lin1 (+V0 GEMM)  ||  degree counts (co-resident occupancy)
    k_lin1cnt<<<NT + nsb, 256, 0, stream>>>(x, w1, b1, wv, bv, xsU, kv0,
                                            ei, counts, E, n, NT);
    // 3. scan
    k_scan<<<1, 1024, 0, stream>>>(counts, startA, dinv, n);
    // 4. scatter  ||  slice-0 K/V staging (4 jobs)
    k_scatter_stage<<<nsb + 4 * NT, 256, 0, stream>>>(
        ei, startA, counts, ebuf, E, nsb, xsU, wk, bk, wv, bv, kv1, kv2, n, NT);
    // 5. layer 0 attention (T=1) -> xs slice 1
    k_attn<1, false><<<attn_grid, 256, 0, stream>>>(
        startA, ebuf, dinv, nullptr, kv0, nullptr, nullptr,
        xsU + sstride, nullptr, n);
    // 6. slice-1 K/V staging + q1 (5 jobs)
    {
        dim3 grid(NT, 5);
        k_stage<<<grid, 256, 0, stream>>>(xsU, sstride, wq, bq, wk, bk, wv, bv,
                                          qbuf, kv1, kv2, n, 1);
    }
    // 7. layer 1 attention (T=2) -> xs slice 2
    k_attn<2, false><<<attn_grid, 256, 0, stream>>>(
        startA, ebuf, dinv, qbuf, kv1, nullptr, nullptr,
        xsU + 2 * sstride, nullptr, n);
    // 8. slice-2 K/V staging + q2 (3 jobs)
    {
        dim3 grid(NT, 3);
        k_stage<<<grid, 256, 0, stream>>>(xsU, sstride, wq, bq, wk, bk, wv, bv,
                                          qbuf, kv1, kv2, n, 2);
    }
    // 9. layer 2 attention (T=3) + final projection + log_softmax
    k_attn<3, true><<<attn_grid, 256, 0, stream>>>(
        startA, ebuf, dinv, qbuf, kv2, w2, b2, nullptr, outp, n);
}

// Round 11
// 256.029 us; speedup vs baseline: 1.0115x; 1.0060x over previous
//
#include <hip/hip_runtime.h>
#include <math.h>

#define HID 64
#define HEADS 8
#define ALD 72

typedef __attribute__((ext_vector_type(8))) short bf16x8;
typedef __attribute__((ext_vector_type(4))) float f32x4;

// ---------------------------------------------------------------------------
// bf16 helpers (storage compression; accumulation stays f32)
// ---------------------------------------------------------------------------
__device__ __forceinline__ unsigned short f2bf(float f) {
    union { float f; unsigned int u; } cv; cv.f = f;
    unsigned int u = cv.u;
    unsigned int r = (u + 0x7FFFu + ((u >> 16) & 1u)) >> 16;  // RNE
    return (unsigned short)r;
}
__device__ __forceinline__ float bflo(unsigned int u) {
    union { unsigned int u; float f; } cv; cv.u = u << 16; return cv.f;
}
__device__ __forceinline__ float bfhi(unsigned int u) {
    union { unsigned int u; float f; } cv; cv.u = u & 0xFFFF0000u; return cv.f;
}
__device__ __forceinline__ unsigned relu_pk(unsigned u) {  // relu on 2 packed bf16
    unsigned m = ((u & 0x8000u) ? 0u : 0xFFFFu) |
                 ((u & 0x80000000u) ? 0u : 0xFFFF0000u);
    return u & m;
}

// packed bf16-pair dot with f32 accumulate: d = a.lo*b.lo + a.hi*b.hi + c
__device__ __forceinline__ float dot2bf(unsigned a, unsigned b, float c) {
    float d;
    asm("v_dot2_f32_bf16 %0, %1, %2, %3" : "=v"(d) : "v"(a), "v"(b), "v"(c));
    return d;
}

// ---------------------------------------------------------------------------
// scan: single 1024-thread block, counts -> start (exclusive), dinv
// ---------------------------------------------------------------------------
__global__ __launch_bounds__(1024) void k_scan(const int* __restrict__ counts,
                                               int* __restrict__ start,
                                               float* __restrict__ dinv, int n) {
    __shared__ int wsum[16];
    int tid = threadIdx.x;
    int lane = tid & 63, wvi = tid >> 6;
    int ipt = (n + 1023) >> 10;
    int c0 = tid * ipt;
    int c1 = min(n, c0 + ipt);
    if (c0 > n) c0 = n;
    int s = 0;
    for (int i = c0; i < c1; ++i) s += counts[i];
    int x = s;
#pragma unroll
    for (int off = 1; off < 64; off <<= 1) {
        int y = __shfl_up(x, off);
        if (lane >= off) x += y;
    }
    if (lane == 63) wsum[wvi] = x;
    __syncthreads();
    if (wvi == 0 && lane < 16) {
        int t2 = wsum[lane];
#pragma unroll
        for (int off = 1; off < 16; off <<= 1) {
            int y = __shfl_up(t2, off);
            if (lane >= off) t2 += y;
        }
        wsum[lane] = t2;
    }
    __syncthreads();
    int waveoff = (wvi > 0) ? wsum[wvi - 1] : 0;
    int run = waveoff + x - s;
    for (int i = c0; i < c1; ++i) {
        int v = counts[i];
        start[i] = run;
        dinv[i] = rsqrtf((float)(v + 1));  // +1 self-loop
        run += v;
    }
    if (tid == 0) start[n] = wsum[15];
}

// ---------------------------------------------------------------------------
// MFMA GEMM core: block = 64 nodes x 64 oc, 4 waves, wave w = 16-row strip.
// stage_w_bf16: coalesced float4 global read (R0/R6 layout); the transposed
// LDS stores alias 2-way across banks which is free on CDNA4.
// ---------------------------------------------------------------------------
__device__ __forceinline__ void stage_w_bf16(unsigned short* Wt,
                                             const float* __restrict__ w, int tid) {
    for (int idx = tid; idx < 1024; idx += 256) {
        int k = idx >> 4, n4 = (idx & 15) * 4;
        float4 wv = *(const float4*)&w[k * 64 + n4];
        Wt[(n4 + 0) * ALD + k] = f2bf(wv.x);
        Wt[(n4 + 1) * ALD + k] = f2bf(wv.y);
        Wt[(n4 + 2) * ALD + k] = f2bf(wv.z);
        Wt[(n4 + 3) * ALD + k] = f2bf(wv.w);
    }
}

__device__ __forceinline__ void mfma_step(const unsigned short* Alds,
                                          const unsigned short* Wt,
                                          int tid, f32x4 acc[4]) {
    int lane = tid & 63;
    int m0 = (tid >> 6) * 16;
    int c16 = lane & 15, quad = lane >> 4;
    const unsigned short* ar = &Alds[(m0 + c16) * ALD + quad * 8];
    bf16x8 a0 = *(const bf16x8*)ar;
    bf16x8 a1 = *(const bf16x8*)(ar + 32);
#pragma unroll
    for (int nt = 0; nt < 4; ++nt) {
        const unsigned short* br = &Wt[(nt * 16 + c16) * ALD + quad * 8];
        bf16x8 b0 = *(const bf16x8*)br;
        bf16x8 b1 = *(const bf16x8*)(br + 32);
        acc[nt] = __builtin_amdgcn_mfma_f32_16x16x32_bf16(a0, b0, acc[nt], 0, 0, 0);
        acc[nt] = __builtin_amdgcn_mfma_f32_16x16x32_bf16(a1, b1, acc[nt], 0, 0, 0);
    }
}

// bf16-src 64x64 GEMM tile body.  qd!=nullptr -> f32 q out; else bf16 kv out.
__device__ __forceinline__ void stage_tile_body(
    const unsigned short* __restrict__ src, const float* __restrict__ w,
    const float* __restrict__ b, float* __restrict__ qd,
    unsigned short* __restrict__ kvdst, int kv_stride, int kv_off, bool relu_in,
    int node0, int n, int tid, unsigned short* Alds, unsigned short* Wt) {
    stage_w_bf16(Wt, w, tid);
    for (int idx = tid; idx < 512; idx += 256) {
        int r = idx >> 3, seg = idx & 7;
        int node = node0 + r;
        uint4 u = make_uint4(0u, 0u, 0u, 0u);
        if (node < n) u = *(const uint4*)&src[(size_t)node * 64 + seg * 8];
        if (relu_in) {
            u.x = relu_pk(u.x); u.y = relu_pk(u.y);
            u.z = relu_pk(u.z); u.w = relu_pk(u.w);
        }
        *(uint4*)&Alds[r * ALD + seg * 8] = u;
    }
    __syncthreads();
    f32x4 acc[4];
#pragma unroll
    for (int nt = 0; nt < 4; ++nt) acc[nt] = (f32x4){0.f, 0.f, 0.f, 0.f};
    mfma_step(Alds, Wt, tid, acc);

    int lane = tid & 63;
    int m0 = (tid >> 6) * 16, c16 = lane & 15, quad = lane >> 4;
    float bias[4];
#pragma unroll
    for (int nt = 0; nt < 4; ++nt) bias[nt] = b[nt * 16 + c16];
    if (qd) {
#pragma unroll
        for (int i = 0; i < 4; ++i) {
            int node = node0 + m0 + quad * 4 + i;
            if (node < n) {
#pragma unroll
                for (int nt = 0; nt < 4; ++nt)
                    qd[(size_t)node * 64 + nt * 16 + c16] = acc[nt][i] + bias[nt];
            }
        }
    } else {
#pragma unroll
        for (int i = 0; i < 4; ++i) {
            int node = node0 + m0 + quad * 4 + i;
            if (node < n) {
#pragma unroll
                for (int nt = 0; nt < 4; ++nt)
                    kvdst[(size_t)node * kv_stride + kv_off + nt * 16 + c16] =
                        f2bf(acc[nt][i] + bias[nt]);
            }
        }
    }
}

// ---------------------------------------------------------------------------
// lin1 (+ fused layer-0 V GEMM) co-scheduled with degree counting:
//   blocks [0, NT):        h = relu(x@W1+b1) -> xs0;  V0 = h@Wv0+bv0 -> kv0
//   blocks [NT, NT+nsb):   atomic degree counts (co-resident occupancy)
// ---------------------------------------------------------------------------
__global__ __launch_bounds__(256, 4) void k_lin1cnt(
    const float* __restrict__ x, const float* __restrict__ w,
    const float* __restrict__ b, const float* __restrict__ wv0,
    const float* __restrict__ bv0, unsigned short* __restrict__ h,
    unsigned short* __restrict__ kv, const int* __restrict__ ei,
    int* __restrict__ counts, int E, int n, int NT) {
    __shared__ __align__(16) unsigned short Alds[64 * ALD];
    __shared__ __align__(16) unsigned short Wt[64 * ALD];
    int tid = threadIdx.x;
    int bx = blockIdx.x;
    if (bx >= NT) {
        int e = (bx - NT) * 256 + tid;
        if (e < E) atomicAdd(&counts[ei[E + e]], 1);
        return;
    }
    int node0 = bx * 64;
    f32x4 acc[4];
#pragma unroll
    for (int nt = 0; nt < 4; ++nt) acc[nt] = (f32x4){0.f, 0.f, 0.f, 0.f};

    for (int kc = 0; kc < 256; kc += 64) {
        __syncthreads();
        stage_w_bf16(Wt, w + kc * 64, tid);
        for (int idx = tid; idx < 1024; idx += 256) {
            int r = idx >> 4, c4 = (idx & 15) * 4;
            int node = node0 + r;
            float4 v = make_float4(0.f, 0.f, 0.f, 0.f);
            if (node < n) v = *(const float4*)&x[(size_t)node * 256 + kc + c4];
            Alds[r * ALD + c4 + 0] = f2bf(v.x);
            Alds[r * ALD + c4 + 1] = f2bf(v.y);
            Alds[r * ALD + c4 + 2] = f2bf(v.z);
            Alds[r * ALD + c4 + 3] = f2bf(v.w);
        }
        __syncthreads();
        mfma_step(Alds, Wt, tid, acc);
    }
    int lane = tid & 63;
    int m0 = (tid >> 6) * 16, c16 = lane & 15, quad = lane >> 4;
    float bias[4];
#pragma unroll
    for (int nt = 0; nt < 4; ++nt) bias[nt] = b[nt * 16 + c16];

    __syncthreads();
    stage_w_bf16(Wt, wv0, tid);
#pragma unroll
    for (int i = 0; i < 4; ++i) {
        int row = m0 + quad * 4 + i;
        int node = node0 + row;
#pragma unroll
        for (int nt = 0; nt < 4; ++nt) {
            unsigned short hb = f2bf(fmaxf(acc[nt][i] + bias[nt], 0.f));
            Alds[row * ALD + nt * 16 + c16] = hb;
            if (node < n) h[(size_t)node * 64 + nt * 16 + c16] = hb;
        }
    }
    __syncthreads();
    f32x4 acc2[4];
#pragma unroll
    for (int nt = 0; nt < 4; ++nt) acc2[nt] = (f32x4){0.f, 0.f, 0.f, 0.f};
    mfma_step(Alds, Wt, tid, acc2);
    float bias2[4];
#pragma unroll
    for (int nt = 0; nt < 4; ++nt) bias2[nt] = bv0[nt * 16 + c16];
#pragma unroll
    for (int i = 0; i < 4; ++i) {
        int node = node0 + m0 + quad * 4 + i;
        if (node < n) {
#pragma unroll
            for (int nt = 0; nt < 4; ++nt)
                kv[(size_t)node * 64 + nt * 16 + c16] = f2bf(acc2[nt][i] + bias2[nt]);
        }
    }
}

// ---------------------------------------------------------------------------
// scatter fused with the 4 slice-0 K/V staging GEMMs.
//   blocks [0, nsb):          CSR scatter (consumes counts via atomicSub)
//   blocks [nsb, nsb+4*NT):   j = (bx-nsb)/NT: {L1K,L1V,L2K,L2V} x s0
// ---------------------------------------------------------------------------
__global__ __launch_bounds__(256, 4) void k_scatter_stage(
    const int* __restrict__ ei, const int* __restrict__ startA,
    int* __restrict__ counts, unsigned short* __restrict__ ebuf, int E, int nsb,
    const unsigned short* __restrict__ xs,
    const float* __restrict__ wk, const float* __restrict__ bk,
    const float* __restrict__ wv, const float* __restrict__ bv,
    unsigned short* __restrict__ kv1, unsigned short* __restrict__ kv2,
    int n, int NT) {
    __shared__ __align__(16) unsigned short Alds[64 * ALD];
    __shared__ __align__(16) unsigned short Wt[64 * ALD];
    int bx = blockIdx.x;
    if (bx < nsb) {
        int e = bx * 256 + threadIdx.x;
        if (e < E) {
            int r = ei[e], c = ei[E + e];
            int pos = startA[c] + atomicSub(&counts[c], 1) - 1;
            ebuf[pos] = (unsigned short)r;
        }
        return;
    }
    int t = bx - nsb;
    int j = t / NT, tile = t - j * NT;
    int layer = 1 + (j >> 1), isV = j & 1;
    const float* w = (isV ? wv : wk) + layer * 4096;
    const float* b = (isV ? bv : bk) + layer * 64;
    unsigned short* dst = (layer == 1) ? kv1 : kv2;
    int stride = (layer == 1) ? 256 : 384;
    int koff = isV ? 64 : 0;
    stage_tile_body(xs, w, b, nullptr, dst, stride, koff, false,
                    tile * 64, n, threadIdx.x, Alds, Wt);
}

// ---------------------------------------------------------------------------
// staging launches between attention layers.
//  phase 1 (5 jobs): {L1K,L1V,L2K,L2V} x s1  +  q(layer1, src s1)
//  phase 2 (3 jobs): {L2K,L2V} x s2          +  q(layer2, src s2)
// ---------------------------------------------------------------------------
__global__ __launch_bounds__(256, 4) void k_stage(
    const unsigned short* __restrict__ xs, size_t sstride,
    const float* __restrict__ wq, const float* __restrict__ bq,
    const float* __restrict__ wk, const float* __restrict__ bk,
    const float* __restrict__ wv, const float* __restrict__ bv,
    float* __restrict__ qbuf, unsigned short* __restrict__ kv1,
    unsigned short* __restrict__ kv2, int n, int phase) {
    __shared__ __align__(16) unsigned short Alds[64 * ALD];
    __shared__ __align__(16) unsigned short Wt[64 * ALD];
    int j = blockIdx.y;
    int layer, s, isV = 0, isQ = 0;
    if (phase == 1) {
        if (j < 4) { layer = 1 + (j >> 1); isV = j & 1; s = 1; }
        else       { layer = 1; isQ = 1; s = 1; }
    } else {
        if (j < 2) { layer = 2; isV = j; s = 2; }
        else       { layer = 2; isQ = 1; s = 2; }
    }
    const unsigned short* src = xs + (size_t)s * sstride;
    const float* w; const float* b;
    float* qd = nullptr; unsigned short* dst = nullptr;
    int stride = 0, koff = 0;
    if (isQ) {
        w = wq + layer * 4096; b = bq + layer * 64; qd = qbuf;
    } else {
        w = (isV ? wv : wk) + layer * 4096;
        b = (isV ? bv : bk) + layer * 64;
        dst = (layer == 1) ? kv1 : kv2;
        stride = (layer == 1) ? 256 : 384;
        koff = s * 128 + (isV ? 64 : 0);
    }
    stage_tile_body(src, w, b, qd, dst, stride, koff, true,
                    blockIdx.x * 64, n, threadIdx.x, Alds, Wt);
}

// ---------------------------------------------------------------------------
// attention + aggregate, CSR by destination.  One wave per node.
// Lane = (edge-slot g = lane>>3, head h = lane&7): 8 edges in flight,
// lane-local dot/softmax.  Edge-chunk loop unrolled 2x so the compiler
// issues two chunks' ebuf/dinv/K/V loads together (2x memory-level
// parallelism, compiler-scheduled — no manual rotation/pinning).
// q from precomputed f32 buffer, packed bf16 pairs for v_dot2_f32_bf16.
// T==1: pure dinv-weighted V gather.  FINAL: fused W2 + log_softmax.
// ---------------------------------------------------------------------------
template <int T, bool FINAL>
__global__ __launch_bounds__(256) void k_attn(
    const int* __restrict__ start, const unsigned short* __restrict__ ebuf,
    const float* __restrict__ dinv, const float* __restrict__ q,
    const unsigned short* __restrict__ kv,
    const float* __restrict__ w2, const float* __restrict__ b2,
    unsigned short* __restrict__ outb, float* __restrict__ outf, int n) {
    const int KVS = (T == 1) ? 64 : T * 128;
    int node = (int)((blockIdx.x * (size_t)blockDim.x + threadIdx.x) >> 6);
    int lane = threadIdx.x & 63;
    if (node >= n) return;
    int g = lane >> 3;
    int cb = (lane & 7) * 8;

    unsigned qpk[4];
    if (T > 1) {
        const float isd = 0.35355339059327373f;  // 1/sqrt(8)
        float4 q0 = *(const float4*)&q[(size_t)node * 64 + cb];
        float4 q1 = *(const float4*)&q[(size_t)node * 64 + cb + 4];
        qpk[0] = ((unsigned)f2bf(q0.y * isd) << 16) | (unsigned)f2bf(q0.x * isd);
        qpk[1] = ((unsigned)f2bf(q0.w * isd) << 16) | (unsigned)f2bf(q0.z * isd);
        qpk[2] = ((unsigned)f2bf(q1.y * isd) << 16) | (unsigned)f2bf(q1.x * isd);
        qpk[3] = ((unsigned)f2bf(q1.w * isd) << 16) | (unsigned)f2bf(q1.z * isd);
    }
    float dc = dinv[node];
    int s0 = start[node];
    int cnt = start[node + 1] - s0 + 1;

    float acc[8];
#pragma unroll
    for (int k = 0; k < 8; ++k) acc[k] = 0.f;

#pragma unroll 2
    for (int base = 0; base < cnt; base += 8) {
        int idx = base + g;
        bool valid = idx < cnt;
        int r = node;
        if (valid && idx > 0) r = ebuf[s0 + idx - 1];
        float dr = valid ? dinv[r] : 0.f;
        const unsigned short* rkv = kv + (size_t)r * KVS;

        float cf[T];
        if (T > 1) {
            float sc[T];
            float m = -1e30f;
#pragma unroll
            for (int s = 0; s < T; ++s) {
                uint4 ku = *(const uint4*)&rkv[s * 128 + cb];
                float p = dot2bf(qpk[3], ku.w,
                          dot2bf(qpk[2], ku.z,
                          dot2bf(qpk[1], ku.y,
                          dot2bf(qpk[0], ku.x, 0.f))));
                sc[s] = p;
                m = fmaxf(m, p);
            }
            float denom = 0.f;
#pragma unroll
            for (int s = 0; s < T; ++s) { sc[s] = __expf(sc[s] - m); denom += sc[s]; }
            float w = dr / denom;
#pragma unroll
            for (int s = 0; s < T; ++s) cf[s] = w * sc[s];
        } else {
            cf[0] = dr;
        }
#pragma unroll
        for (int s = 0; s < T; ++s) {
            uint4 vu = *(const uint4*)&rkv[((T == 1) ? 0 : s * 128 + 64) + cb];
            float wv_ = cf[s];
            acc[0] += wv_ * bflo(vu.x); acc[1] += wv_ * bfhi(vu.x);
            acc[2] += wv_ * bflo(vu.y); acc[3] += wv_ * bfhi(vu.y);
            acc[4] += wv_ * bflo(vu.z); acc[5] += wv_ * bfhi(vu.z);
            acc[6] += wv_ * bflo(vu.w); acc[7] += wv_ * bfhi(vu.w);
        }
    }

#pragma unroll
    for (int off = 8; off < 64; off <<= 1) {
#pragma unroll
        for (int k = 0; k < 8; ++k) acc[k] += __shfl_xor(acc[k], off);
    }

    if (!FINAL) {
        if (g == 0) {
            ushort4 o0, o1;
            o0.x = f2bf(acc[0] * dc); o0.y = f2bf(acc[1] * dc);
            o0.z = f2bf(acc[2] * dc); o0.w = f2bf(acc[3] * dc);
            o1.x = f2bf(acc[4] * dc); o1.y = f2bf(acc[5] * dc);
            o1.z = f2bf(acc[6] * dc); o1.w = f2bf(acc[7] * dc);
            *(ushort4*)&outb[(size_t)node * 64 + cb] = o0;
            *(ushort4*)&outb[(size_t)node * 64 + cb + 4] = o1;
        }
    } else {
        // every lane holds the full row: channel c on lane (c>>3), reg acc[c&7]
        float lg = b2[lane];
#pragma unroll
        for (int c = 0; c < 64; ++c) {
            float xc = fmaxf(__shfl(acc[c & 7], c >> 3) * dc, 0.f);
            lg += xc * w2[c * 64 + lane];
        }
        float mx = lg;
#pragma unroll
        for (int off = 1; off < 64; off <<= 1) mx = fmaxf(mx, __shfl_xor(mx, off));
        float e = __expf(lg - mx);
        float ssum = e;
#pragma unroll
        for (int off = 1; off < 64; off <<= 1) ssum += __shfl_xor(ssum, off);
        outf[(size_t)node * 64 + lane] = lg - mx - __logf(ssum);
    }
}

// ---------------------------------------------------------------------------
extern "C" void kernel_launch(void* const* d_in, const int* in_sizes, int n_in,
                              void* d_out, int out_size, void* d_ws, size_t ws_size,
                              hipStream_t stream) {
    const float* x  = (const float*)d_in[0];
    const int*   ei = (const int*)d_in[1];
    const float* w1 = (const float*)d_in[2];
    const float* b1 = (const float*)d_in[3];
    const float* wq = (const float*)d_in[4];
    const float* bq = (const float*)d_in[5];
    const float* wk = (const float*)d_in[6];
    const float* bk = (const float*)d_in[7];
    const float* wv = (const float*)d_in[8];
    const float* bv = (const float*)d_in[9];
    const float* w2 = (const float*)d_in[10];
    const float* b2 = (const float*)d_in[11];
    float* outp = (float*)d_out;

    int n = in_sizes[0] / 256;
    int E = in_sizes[1] / 2;

    float* ws = (float*)d_ws;
    size_t off = 0;
    float* dinv = ws + off; off += (size_t)n;
    float* qbuf = ws + off; off += (size_t)n * 64;
    unsigned short* xsU = (unsigned short*)(ws + off); off += (size_t)n * 96;   // 3 slices bf16
    unsigned short* kv0 = (unsigned short*)(ws + off); off += (size_t)n * 32;   // n*64 bf16
    unsigned short* kv1 = (unsigned short*)(ws + off); off += (size_t)n * 128;  // n*256 bf16
    unsigned short* kv2 = (unsigned short*)(ws + off); off += (size_t)n * 192;  // n*384 bf16
    int* wsI    = (int*)(ws + off);
    int* counts = wsI;                      // n
    int* startA = wsI + n;                  // n+1
    unsigned short* ebuf = (unsigned short*)(wsI + 2 * n + 1);  // E u16

    size_t sstride = (size_t)n * 64;
    int NT = (n + 63) / 64;
    int nsb = (E + 255) / 256;
    int attn_grid = (int)(((size_t)n * 64 + 255) / 256);

    // 1. zero counts
    hipMemsetAsync(counts, 0, (size_t)n * sizeof(int), stream);
    // 2. lin1 (+V0 GEMM)  ||  degree counts (co-resident occupancy)
    k_lin1cnt<<<NT + nsb, 256, 0, stream>>>(x, w1, b1, wv, bv, xsU, kv0,
                                            ei, counts, E, n, NT);
    // 3. scan
    k_scan<<<1, 1024, 0, stream>>>(counts, startA, dinv, n);
    // 4. scatter  ||  slice-0 K/V staging (4 jobs)
    k_scatter_stage<<<nsb + 4 * NT, 256, 0, stream>>>(
        ei, startA, counts, ebuf, E, nsb, xsU, wk, bk, wv, bv, kv1, kv2, n, NT);
    // 5. layer 0 attention (T=1) -> xs slice 1
    k_attn<1, false><<<attn_grid, 256, 0, stream>>>(
        startA, ebuf, dinv, nullptr, kv0, nullptr, nullptr,
        xsU + sstride, nullptr, n);
    // 6. slice-1 K/V staging + q1 (5 jobs)
    {
        dim3 grid(NT, 5);
        k_stage<<<grid, 256, 0, stream>>>(xsU, sstride, wq, bq, wk, bk, wv, bv,
                                          qbuf, kv1, kv2, n, 1);
    }
    // 7. layer 1 attention (T=2) -> xs slice 2
    k_attn<2, false><<<attn_grid, 256, 0, stream>>>(
        startA, ebuf, dinv, qbuf, kv1, nullptr, nullptr,
        xsU + 2 * sstride, nullptr, n);
    // 8. slice-2 K/V staging + q2 (3 jobs)
    {
        dim3 grid(NT, 3);
        k_stage<<<grid, 256, 0, stream>>>(xsU, sstride, wq, bq, wk, bk, wv, bv,
                                          qbuf, kv1, kv2, n, 2);
    }
    // 9. layer 2 attention (T=3) + final projection + log_softmax
    k_attn<3, true><<<attn_grid, 256, 0, stream>>>(
        startA, ebuf, dinv, qbuf, kv2, w2, b2, nullptr, outp, n);
}

// Round 13
// 254.449 us; speedup vs baseline: 1.0178x; 1.0062x over previous
//
#include <hip/hip_runtime.h>
#include <math.h>

#define HID 64
#define HEADS 8
#define ALD 72

typedef __attribute__((ext_vector_type(8))) _Float16 f16x8;
typedef __attribute__((ext_vector_type(4))) float f32x4;

// ---------------------------------------------------------------------------
// fp16 helpers (storage compression; accumulation stays f32).
// fp16 (10-bit mantissa) is MORE accurate than bf16 for the O(1) magnitudes
// here, and enables v_fma_mix_f32 / v_dot2_f32_f16 packed ops.
// ---------------------------------------------------------------------------
__device__ __forceinline__ unsigned short f2h(float f) {
    _Float16 h = (_Float16)f;  // v_cvt_f16_f32, RNE
    union { _Float16 h; unsigned short u; } cv; cv.h = h; return cv.u;
}
__device__ __forceinline__ unsigned relu_pk(unsigned u) {  // relu on 2 packed f16
    unsigned m = ((u & 0x8000u) ? 0u : 0xFFFFu) |
                 ((u & 0x80000000u) ? 0u : 0xFFFF0000u);
    return u & m;
}

// packed f16-pair dot with f32 accumulate: d = a.lo*b.lo + a.hi*b.hi + c
__device__ __forceinline__ float dot2h(unsigned a, unsigned b, float c) {
    float d;
    asm("v_dot2_f32_f16 %0, %1, %2, %3" : "=v"(d) : "v"(a), "v"(b), "v"(c));
    return d;
}

// acc_lo += c * f16_lo(w);  acc_hi += c * f16_hi(w)   (v_fma_mix_f32, 1 op each)
__device__ __forceinline__ void fmix2(float c, unsigned w, float& alo, float& ahi) {
    asm("v_fma_mix_f32 %0, %1, %2, %0 op_sel:[0,0,0] op_sel_hi:[0,1,0]"
        : "+v"(alo) : "v"(c), "v"(w));
    asm("v_fma_mix_f32 %0, %1, %2, %0 op_sel:[0,1,0] op_sel_hi:[0,1,0]"
        : "+v"(ahi) : "v"(c), "v"(w));
}

// ---------------------------------------------------------------------------
// scan: single 1024-thread block, counts -> start (exclusive), dinv
// ---------------------------------------------------------------------------
__global__ __launch_bounds__(1024) void k_scan(const int* __restrict__ counts,
                                               int* __restrict__ start,
                                               float* __restrict__ dinv, int n) {
    __shared__ int wsum[16];
    int tid = threadIdx.x;
    int lane = tid & 63, wvi = tid >> 6;
    int ipt = (n + 1023) >> 10;
    int c0 = tid * ipt;
    int c1 = min(n, c0 + ipt);
    if (c0 > n) c0 = n;
    int s = 0;
    for (int i = c0; i < c1; ++i) s += counts[i];
    int x = s;
#pragma unroll
    for (int off = 1; off < 64; off <<= 1) {
        int y = __shfl_up(x, off);
        if (lane >= off) x += y;
    }
    if (lane == 63) wsum[wvi] = x;
    __syncthreads();
    if (wvi == 0 && lane < 16) {
        int t2 = wsum[lane];
#pragma unroll
        for (int off = 1; off < 16; off <<= 1) {
            int y = __shfl_up(t2, off);
            if (lane >= off) t2 += y;
        }
        wsum[lane] = t2;
    }
    __syncthreads();
    int waveoff = (wvi > 0) ? wsum[wvi - 1] : 0;
    int run = waveoff + x - s;
    for (int i = c0; i < c1; ++i) {
        int v = counts[i];
        start[i] = run;
        dinv[i] = rsqrtf((float)(v + 1));  // +1 self-loop
        run += v;
    }
    if (tid == 0) start[n] = wsum[15];
}

// ---------------------------------------------------------------------------
// MFMA GEMM core: block = 64 nodes x 64 oc, 4 waves, wave w = 16-row strip.
// stage_w_f16: coalesced float4 global read; the transposed LDS stores alias
// 2-way across banks which is free on CDNA4.
// ---------------------------------------------------------------------------
__device__ __forceinline__ void stage_w_f16(unsigned short* Wt,
                                            const float* __restrict__ w, int tid) {
    for (int idx = tid; idx < 1024; idx += 256) {
        int k = idx >> 4, n4 = (idx & 15) * 4;
        float4 wv = *(const float4*)&w[k * 64 + n4];
        Wt[(n4 + 0) * ALD + k] = f2h(wv.x);
        Wt[(n4 + 1) * ALD + k] = f2h(wv.y);
        Wt[(n4 + 2) * ALD + k] = f2h(wv.z);
        Wt[(n4 + 3) * ALD + k] = f2h(wv.w);
    }
}

__device__ __forceinline__ void mfma_step(const unsigned short* Alds,
                                          const unsigned short* Wt,
                                          int tid, f32x4 acc[4]) {
    int lane = tid & 63;
    int m0 = (tid >> 6) * 16;
    int c16 = lane & 15, quad = lane >> 4;
    const unsigned short* ar = &Alds[(m0 + c16) * ALD + quad * 8];
    f16x8 a0 = *(const f16x8*)ar;
    f16x8 a1 = *(const f16x8*)(ar + 32);
#pragma unroll
    for (int nt = 0; nt < 4; ++nt) {
        const unsigned short* br = &Wt[(nt * 16 + c16) * ALD + quad * 8];
        f16x8 b0 = *(const f16x8*)br;
        f16x8 b1 = *(const f16x8*)(br + 32);
        acc[nt] = __builtin_amdgcn_mfma_f32_16x16x32_f16(a0, b0, acc[nt], 0, 0, 0);
        acc[nt] = __builtin_amdgcn_mfma_f32_16x16x32_f16(a1, b1, acc[nt], 0, 0, 0);
    }
}

// f16-src 64x64 GEMM tile body.  qd!=nullptr -> f32 q out; else f16 kv out.
__device__ __forceinline__ void stage_tile_body(
    const unsigned short* __restrict__ src, const float* __restrict__ w,
    const float* __restrict__ b, float* __restrict__ qd,
    unsigned short* __restrict__ kvdst, int kv_stride, int kv_off, bool relu_in,
    int node0, int n, int tid, unsigned short* Alds, unsigned short* Wt) {
    stage_w_f16(Wt, w, tid);
    for (int idx = tid; idx < 512; idx += 256) {
        int r = idx >> 3, seg = idx & 7;
        int node = node0 + r;
        uint4 u = make_uint4(0u, 0u, 0u, 0u);
        if (node < n) u = *(const uint4*)&src[(size_t)node * 64 + seg * 8];
        if (relu_in) {
            u.x = relu_pk(u.x); u.y = relu_pk(u.y);
            u.z = relu_pk(u.z); u.w = relu_pk(u.w);
        }
        *(uint4*)&Alds[r * ALD + seg * 8] = u;
    }
    __syncthreads();
    f32x4 acc[4];
#pragma unroll
    for (int nt = 0; nt < 4; ++nt) acc[nt] = (f32x4){0.f, 0.f, 0.f, 0.f};
    mfma_step(Alds, Wt, tid, acc);

    int lane = tid & 63;
    int m0 = (tid >> 6) * 16, c16 = lane & 15, quad = lane >> 4;
    float bias[4];
#pragma unroll
    for (int nt = 0; nt < 4; ++nt) bias[nt] = b[nt * 16 + c16];
    if (qd) {
#pragma unroll
        for (int i = 0; i < 4; ++i) {
            int node = node0 + m0 + quad * 4 + i;
            if (node < n) {
#pragma unroll
                for (int nt = 0; nt < 4; ++nt)
                    qd[(size_t)node * 64 + nt * 16 + c16] = acc[nt][i] + bias[nt];
            }
        }
    } else {
#pragma unroll
        for (int i = 0; i < 4; ++i) {
            int node = node0 + m0 + quad * 4 + i;
            if (node < n) {
#pragma unroll
                for (int nt = 0; nt < 4; ++nt)
                    kvdst[(size_t)node * kv_stride + kv_off + nt * 16 + c16] =
                        f2h(acc[nt][i] + bias[nt]);
            }
        }
    }
}

// ---------------------------------------------------------------------------
// lin1 (+ fused layer-0 V GEMM) co-scheduled with degree counting:
//   blocks [0, NT):        h = relu(x@W1+b1) -> xs0;  V0 = h@Wv0+bv0 -> kv0
//   blocks [NT, NT+nsb):   atomic degree counts (co-resident occupancy)
// ---------------------------------------------------------------------------
__global__ __launch_bounds__(256, 4) void k_lin1cnt(
    const float* __restrict__ x, const float* __restrict__ w,
    const float* __restrict__ b, const float* __restrict__ wv0,
    const float* __restrict__ bv0, unsigned short* __restrict__ h,
    unsigned short* __restrict__ kv, const int* __restrict__ ei,
    int* __restrict__ counts, int E, int n, int NT) {
    __shared__ __align__(16) unsigned short Alds[64 * ALD];
    __shared__ __align__(16) unsigned short Wt[64 * ALD];
    int tid = threadIdx.x;
    int bx = blockIdx.x;
    if (bx >= NT) {
        int e = (bx - NT) * 256 + tid;
        if (e < E) atomicAdd(&counts[ei[E + e]], 1);
        return;
    }
    int node0 = bx * 64;
    f32x4 acc[4];
#pragma unroll
    for (int nt = 0; nt < 4; ++nt) acc[nt] = (f32x4){0.f, 0.f, 0.f, 0.f};

    for (int kc = 0; kc < 256; kc += 64) {
        __syncthreads();
        stage_w_f16(Wt, w + kc * 64, tid);
        for (int idx = tid; idx < 1024; idx += 256) {
            int r = idx >> 4, c4 = (idx & 15) * 4;
            int node = node0 + r;
            float4 v = make_float4(0.f, 0.f, 0.f, 0.f);
            if (node < n) v = *(const float4*)&x[(size_t)node * 256 + kc + c4];
            Alds[r * ALD + c4 + 0] = f2h(v.x);
            Alds[r * ALD + c4 + 1] = f2h(v.y);
            Alds[r * ALD + c4 + 2] = f2h(v.z);
            Alds[r * ALD + c4 + 3] = f2h(v.w);
        }
        __syncthreads();
        mfma_step(Alds, Wt, tid, acc);
    }
    int lane = tid & 63;
    int m0 = (tid >> 6) * 16, c16 = lane & 15, quad = lane >> 4;
    float bias[4];
#pragma unroll
    for (int nt = 0; nt < 4; ++nt) bias[nt] = b[nt * 16 + c16];

    __syncthreads();
    stage_w_f16(Wt, wv0, tid);
#pragma unroll
    for (int i = 0; i < 4; ++i) {
        int row = m0 + quad * 4 + i;
        int node = node0 + row;
#pragma unroll
        for (int nt = 0; nt < 4; ++nt) {
            unsigned short hb = f2h(fmaxf(acc[nt][i] + bias[nt], 0.f));
            Alds[row * ALD + nt * 16 + c16] = hb;
            if (node < n) h[(size_t)node * 64 + nt * 16 + c16] = hb;
        }
    }
    __syncthreads();
    f32x4 acc2[4];
#pragma unroll
    for (int nt = 0; nt < 4; ++nt) acc2[nt] = (f32x4){0.f, 0.f, 0.f, 0.f};
    mfma_step(Alds, Wt, tid, acc2);
    float bias2[4];
#pragma unroll
    for (int nt = 0; nt < 4; ++nt) bias2[nt] = bv0[nt * 16 + c16];
#pragma unroll
    for (int i = 0; i < 4; ++i) {
        int node = node0 + m0 + quad * 4 + i;
        if (node < n) {
#pragma unroll
            for (int nt = 0; nt < 4; ++nt)
                kv[(size_t)node * 64 + nt * 16 + c16] = f2h(acc2[nt][i] + bias2[nt]);
        }
    }
}

// ---------------------------------------------------------------------------
// scatter fused with the 4 slice-0 K/V staging GEMMs.
//   blocks [0, nsb):          CSR scatter (consumes counts via atomicSub)
//   blocks [nsb, nsb+4*NT):   j = (bx-nsb)/NT: {L1K,L1V,L2K,L2V} x s0
// ---------------------------------------------------------------------------
__global__ __launch_bounds__(256, 4) void k_scatter_stage(
    const int* __restrict__ ei, const int* __restrict__ startA,
    int* __restrict__ counts, unsigned short* __restrict__ ebuf, int E, int nsb,
    const unsigned short* __restrict__ xs,
    const float* __restrict__ wk, const float* __restrict__ bk,
    const float* __restrict__ wv, const float* __restrict__ bv,
    unsigned short* __restrict__ kv1, unsigned short* __restrict__ kv2,
    int n, int NT) {
    __shared__ __align__(16) unsigned short Alds[64 * ALD];
    __shared__ __align__(16) unsigned short Wt[64 * ALD];
    int bx = blockIdx.x;
    if (bx < nsb) {
        int e = bx * 256 + threadIdx.x;
        if (e < E) {
            int r = ei[e], c = ei[E + e];
            int pos = startA[c] + atomicSub(&counts[c], 1) - 1;
            ebuf[pos] = (unsigned short)r;
        }
        return;
    }
    int t = bx - nsb;
    int j = t / NT, tile = t - j * NT;
    int layer = 1 + (j >> 1), isV = j & 1;
    const float* w = (isV ? wv : wk) + layer * 4096;
    const float* b = (isV ? bv : bk) + layer * 64;
    unsigned short* dst = (layer == 1) ? kv1 : kv2;
    int stride = (layer == 1) ? 256 : 384;
    int koff = isV ? 64 : 0;
    stage_tile_body(xs, w, b, nullptr, dst, stride, koff, false,
                    tile * 64, n, threadIdx.x, Alds, Wt);
}

// ---------------------------------------------------------------------------
// staging launches between attention layers.
//  phase 1 (5 jobs): {L1K,L1V,L2K,L2V} x s1  +  q(layer1, src s1)
//  phase 2 (3 jobs): {L2K,L2V} x s2          +  q(layer2, src s2)
// ---------------------------------------------------------------------------
__global__ __launch_bounds__(256, 4) void k_stage(
    const unsigned short* __restrict__ xs, size_t sstride,
    const float* __restrict__ wq, const float* __restrict__ bq,
    const float* __restrict__ wk, const float* __restrict__ bk,
    const float* __restrict__ wv, const float* __restrict__ bv,
    float* __restrict__ qbuf, unsigned short* __restrict__ kv1,
    unsigned short* __restrict__ kv2, int n, int phase) {
    __shared__ __align__(16) unsigned short Alds[64 * ALD];
    __shared__ __align__(16) unsigned short Wt[64 * ALD];
    int j = blockIdx.y;
    int layer, s, isV = 0, isQ = 0;
    if (phase == 1) {
        if (j < 4) { layer = 1 + (j >> 1); isV = j & 1; s = 1; }
        else       { layer = 1; isQ = 1; s = 1; }
    } else {
        if (j < 2) { layer = 2; isV = j; s = 2; }
        else       { layer = 2; isQ = 1; s = 2; }
    }
    const unsigned short* src = xs + (size_t)s * sstride;
    const float* w; const float* b;
    float* qd = nullptr; unsigned short* dst = nullptr;
    int stride = 0, koff = 0;
    if (isQ) {
        w = wq + layer * 4096; b = bq + layer * 64; qd = qbuf;
    } else {
        w = (isV ? wv : wk) + layer * 4096;
        b = (isV ? bv : bk) + layer * 64;
        dst = (layer == 1) ? kv1 : kv2;
        stride = (layer == 1) ? 256 : 384;
        koff = s * 128 + (isV ? 64 : 0);
    }
    stage_tile_body(src, w, b, qd, dst, stride, koff, true,
                    blockIdx.x * 64, n, threadIdx.x, Alds, Wt);
}

// ---------------------------------------------------------------------------
// attention + aggregate, CSR by destination.  One wave per node.
// Lane = (edge-slot g = lane>>3, head h = lane&7): 8 edges in flight,
// lane-local dot/softmax.  K-dots via v_dot2_f32_f16 (q packed f16 pairs,
// isd folded); V accumulation via v_fma_mix_f32 (1 op per element instead
// of unpack+fma — the largest VALU block in the old bf16 inner loop).
// T==1: pure dinv-weighted V gather.  FINAL: fused W2 + log_softmax.
// ---------------------------------------------------------------------------
template <int T, bool FINAL>
__global__ __launch_bounds__(256) void k_attn(
    const int* __restrict__ start, const unsigned short* __restrict__ ebuf,
    const float* __restrict__ dinv, const float* __restrict__ q,
    const unsigned short* __restrict__ kv,
    const float* __restrict__ w2, const float* __restrict__ b2,
    unsigned short* __restrict__ outb, float* __restrict__ outf, int n) {
    const int KVS = (T == 1) ? 64 : T * 128;
    int node = (int)((blockIdx.x * (size_t)blockDim.x + threadIdx.x) >> 6);
    int lane = threadIdx.x & 63;
    if (node >= n) return;
    int g = lane >> 3;
    int cb = (lane & 7) * 8;

    unsigned qpk[4];
    if (T > 1) {
        const float isd = 0.35355339059327373f;  // 1/sqrt(8)
        float4 q0 = *(const float4*)&q[(size_t)node * 64 + cb];
        float4 q1 = *(const float4*)&q[(size_t)node * 64 + cb + 4];
        qpk[0] = ((unsigned)f2h(q0.y * isd) << 16) | (unsigned)f2h(q0.x * isd);
        qpk[1] = ((unsigned)f2h(q0.w * isd) << 16) | (unsigned)f2h(q0.z * isd);
        qpk[2] = ((unsigned)f2h(q1.y * isd) << 16) | (unsigned)f2h(q1.x * isd);
        qpk[3] = ((unsigned)f2h(q1.w * isd) << 16) | (unsigned)f2h(q1.z * isd);
    }
    float dc = dinv[node];
    int s0 = start[node];
    int cnt = start[node + 1] - s0 + 1;

    float acc[8];
#pragma unroll
    for (int k = 0; k < 8; ++k) acc[k] = 0.f;

#pragma unroll 2
    for (int base = 0; base < cnt; base += 8) {
        int idx = base + g;
        bool valid = idx < cnt;
        int r = node;
        if (valid && idx > 0) r = ebuf[s0 + idx - 1];
        float dr = valid ? dinv[r] : 0.f;
        const unsigned short* rkv = kv + (size_t)r * KVS;

        float cf[T];
        if (T > 1) {
            float sc[T];
            float m = -1e30f;
#pragma unroll
            for (int s = 0; s < T; ++s) {
                uint4 ku = *(const uint4*)&rkv[s * 128 + cb];
                float p = dot2h(qpk[3], ku.w,
                          dot2h(qpk[2], ku.z,
                          dot2h(qpk[1], ku.y,
                          dot2h(qpk[0], ku.x, 0.f))));
                sc[s] = p;
                m = fmaxf(m, p);
            }
            float denom = 0.f;
#pragma unroll
            for (int s = 0; s < T; ++s) { sc[s] = __expf(sc[s] - m); denom += sc[s]; }
            float w = dr / denom;
#pragma unroll
            for (int s = 0; s < T; ++s) cf[s] = w * sc[s];
        } else {
            cf[0] = dr;
        }
#pragma unroll
        for (int s = 0; s < T; ++s) {
            uint4 vu = *(const uint4*)&rkv[((T == 1) ? 0 : s * 128 + 64) + cb];
            fmix2(cf[s], vu.x, acc[0], acc[1]);
            fmix2(cf[s], vu.y, acc[2], acc[3]);
            fmix2(cf[s], vu.z, acc[4], acc[5]);
            fmix2(cf[s], vu.w, acc[6], acc[7]);
        }
    }

#pragma unroll
    for (int off = 8; off < 64; off <<= 1) {
#pragma unroll
        for (int k = 0; k < 8; ++k) acc[k] += __shfl_xor(acc[k], off);
    }

    if (!FINAL) {
        if (g == 0) {
            ushort4 o0, o1;
            o0.x = f2h(acc[0] * dc); o0.y = f2h(acc[1] * dc);
            o0.z = f2h(acc[2] * dc); o0.w = f2h(acc[3] * dc);
            o1.x = f2h(acc[4] * dc); o1.y = f2h(acc[5] * dc);
            o1.z = f2h(acc[6] * dc); o1.w = f2h(acc[7] * dc);
            *(ushort4*)&outb[(size_t)node * 64 + cb] = o0;
            *(ushort4*)&outb[(size_t)node * 64 + cb + 4] = o1;
        }
    } else {
        // every lane holds the full row: channel c on lane (c>>3), reg acc[c&7]
        float lg = b2[lane];
#pragma unroll
        for (int c = 0; c < 64; ++c) {
            float xc = fmaxf(__shfl(acc[c & 7], c >> 3) * dc, 0.f);
            lg += xc * w2[c * 64 + lane];
        }
        float mx = lg;
#pragma unroll
        for (int off = 1; off < 64; off <<= 1) mx = fmaxf(mx, __shfl_xor(mx, off));
        float e = __expf(lg - mx);
        float ssum = e;
#pragma unroll
        for (int off = 1; off < 64; off <<= 1) ssum += __shfl_xor(ssum, off);
        outf[(size_t)node * 64 + lane] = lg - mx - __logf(ssum);
    }
}

// ---------------------------------------------------------------------------
extern "C" void kernel_launch(void* const* d_in, const int* in_sizes, int n_in,
                              void* d_out, int out_size, void* d_ws, size_t ws_size,
                              hipStream_t stream) {
    const float* x  = (const float*)d_in[0];
    const int*   ei = (const int*)d_in[1];
    const float* w1 = (const float*)d_in[2];
    const float* b1 = (const float*)d_in[3];
    const float* wq = (const float*)d_in[4];
    const float* bq = (const float*)d_in[5];
    const float* wk = (const float*)d_in[6];
    const float* bk = (const float*)d_in[7];
    const float* wv = (const float*)d_in[8];
    const float* bv = (const float*)d_in[9];
    const float* w2 = (const float*)d_in[10];
    const float* b2 = (const float*)d_in[11];
    float* outp = (float*)d_out;

    int n = in_sizes[0] / 256;
    int E = in_sizes[1] / 2;

    float* ws = (float*)d_ws;
    size_t off = 0;
    float* dinv = ws + off; off += (size_t)n;
    float* qbuf = ws + off; off += (size_t)n * 64;
    unsigned short* xsU = (unsigned short*)(ws + off); off += (size_t)n * 96;   // 3 slices f16
    unsigned short* kv0 = (unsigned short*)(ws + off); off += (size_t)n * 32;   // n*64 f16
    unsigned short* kv1 = (unsigned short*)(ws + off); off += (size_t)n * 128;  // n*256 f16
    unsigned short* kv2 = (unsigned short*)(ws + off); off += (size_t)n * 192;  // n*384 f16
    int* wsI    = (int*)(ws + off);
    int* counts = wsI;                      // n
    int* startA = wsI + n;                  // n+1
    unsigned short* ebuf = (unsigned short*)(wsI + 2 * n + 1);  // E u16

    size_t sstride = (size_t)n * 64;
    int NT = (n + 63) / 64;
    int nsb = (E + 255) / 256;
    int attn_grid = (int)(((size_t)n * 64 + 255) / 256);

    // 1. zero counts
    hipMemsetAsync(counts, 0, (size_t)n * sizeof(int), stream);
    // 2. lin1 (+V0 GEMM)  ||  degree counts (co-resident occupancy)
    k_lin1cnt<<<NT + nsb, 256, 0, stream>>>(x, w1, b1, wv, bv, xsU, kv0,
                                            ei, counts, E, n, NT);
    // 3. scan
    k_scan<<<1, 1024, 0, stream>>>(counts, startA, dinv, n);
    // 4. scatter  ||  slice-0 K/V staging (4 jobs)
    k_scatter_stage<<<nsb + 4 * NT, 256, 0, stream>>>(
        ei, startA, counts, ebuf, E, nsb, xsU, wk, bk, wv, bv, kv1, kv2, n, NT);
    // 5. layer 0 attention (T=1) -> xs slice 1
    k_attn<1, false><<<attn_grid, 256, 0, stream>>>(
        startA, ebuf, dinv, nullptr, kv0, nullptr, nullptr,
        xsU + sstride, nullptr, n);
    // 6. slice-1 K/V staging + q1 (5 jobs)
    {
        dim3 grid(NT, 5);
        k_stage<<<grid, 256, 0, stream>>>(xsU, sstride, wq, bq, wk, bk, wv, bv,
                                          qbuf, kv1, kv2, n, 1);
    }
    // 7. layer 1 attention (T=2) -> xs slice 2
    k_attn<2, false><<<attn_grid, 256, 0, stream>>>(
        startA, ebuf, dinv, qbuf, kv1, nullptr, nullptr,
        xsU + 2 * sstride, nullptr, n);
    // 8. slice-2 K/V staging + q2 (3 jobs)
    {
        dim3 grid(NT, 3);
        k_stage<<<grid, 256, 0, stream>>>(xsU, sstride, wq, bq, wk, bk, wv, bv,
                                          qbuf, kv1, kv2, n, 2);
    }
    // 9. layer 2 attention (T=3) + final projection + log_softmax
    k_attn<3, true><<<attn_grid, 256, 0, stream>>>(
        startA, ebuf, dinv, qbuf, kv2, w2, b2, nullptr, outp, n);
}